// Round 3
// baseline (447.834 us; speedup 1.0000x reference)
//
#include <hip/hip_runtime.h>
#include <hip/hip_bf16.h>

// Problem constants (BS=2, SLEN=2048, DIM=2048, H=16, DH=128)
// I/O dtype: fp32. Internals: bf16 MFMA, fp32 accumulation, bf16 workspace.
#define S_LEN 2048
#define DIMN  2048
#define NHEAD 16
#define DHEAD 128
#define SEGQ  ((size_t)4096 * 2048)
#define SEGW  ((size_t)2048 * 2048)

typedef __attribute__((ext_vector_type(8))) short short8;
typedef __attribute__((ext_vector_type(4))) float floatx4;

__device__ inline float bf2f(unsigned short u) {
    union { unsigned int i; float f; } v; v.i = ((unsigned int)u) << 16; return v.f;
}
__device__ inline unsigned short f2bf(float f) {
    unsigned int x = __float_as_uint(f);
    unsigned int r = (x + 0x7FFFu + ((x >> 16) & 1u)) >> 16;  // RNE
    return (unsigned short)r;
}
__device__ inline short8 ld8_f32_as_bf16(const float* p) {
    float4 a = *(const float4*)p;
    float4 b = *(const float4*)(p + 4);
    short8 r;
    r[0] = (short)f2bf(a.x); r[1] = (short)f2bf(a.y);
    r[2] = (short)f2bf(a.z); r[3] = (short)f2bf(a.w);
    r[4] = (short)f2bf(b.x); r[5] = (short)f2bf(b.y);
    r[6] = (short)f2bf(b.z); r[7] = (short)f2bf(b.w);
    return r;
}
// Async global->LDS, 16B/lane; LDS base wave-uniform, lane i at +i*16.
__device__ inline void glds16(unsigned short* lds, const unsigned short* g) {
    __builtin_amdgcn_global_load_lds(
        (const __attribute__((address_space(1))) unsigned int*)g,
        (__attribute__((address_space(3))) unsigned int*)lds, 16, 0, 0);
}

// ---------------------------------------------------------------------------
// One-shot fp32 -> bf16 conversion of x, Wq, Wk, Wv, Wo (blockIdx.y selects).
// ---------------------------------------------------------------------------
__global__ __launch_bounds__(256) void cvt5_kernel(
    const float* __restrict__ s0, const float* __restrict__ s1,
    const float* __restrict__ s2, const float* __restrict__ s3,
    const float* __restrict__ s4,
    unsigned short* __restrict__ d0, unsigned short* __restrict__ d1,
    unsigned short* __restrict__ d2, unsigned short* __restrict__ d3,
    unsigned short* __restrict__ d4)
{
    const float* s; unsigned short* d; size_t n;
    switch (blockIdx.y) {
        case 0:  s = s0; d = d0; n = SEGQ; break;
        case 1:  s = s1; d = d1; n = SEGW; break;
        case 2:  s = s2; d = d2; n = SEGW; break;
        case 3:  s = s3; d = d3; n = SEGW; break;
        default: s = s4; d = d4; n = SEGW; break;
    }
    size_t stride = (size_t)gridDim.x * 256 * 8;
    for (size_t i = ((size_t)blockIdx.x * 256 + threadIdx.x) * 8; i < n; i += stride)
        *(short8*)&d[i] = ld8_f32_as_bf16(&s[i]);
}

// ---------------------------------------------------------------------------
// gemm4: counted-vmcnt pipelined bf16 GEMM, 128x64 wave tiles (ratio 42.7).
//   BM=256, BN=128, BK=32, 256 threads = 4 waves (2M x 2N), 128x64 per wave.
//   R2's verified 3-buffer schedule: stage K-tile t+2 while computing t; ONE
//   raw s_barrier + ONE counted s_waitcnt vmcnt(6) per K-tile (6 glds/wave/
//   tile stay in flight; tail vmcnt(0)); sched_barrier(0) pins reads below
//   the barrier. LDS 3 x 24 KB = 72 KB -> 2 blocks/CU (cross-block overlap).
//   Why 128x64 waves: LDS-read FLOP/byte = WM*WN/(WM+WN) = 42.7 > 36 needed
//   to feed the MFMA pipe (64x64's 32 made LDS a co-limiter -> R2's 31.6%
//   MfmaUtil). 12 ds_reads issue back-to-back; compiler's counted lgkmcnt
//   starts the first MFMAs while the last reads drain.
//   Swizzle (unchanged from R2, verified): LDS[row][cb]=global[row][cb^S],
//   S(row)=((row>>1)&3)<<3 elems; staging col colE = (l&3)*8 ^ ((l>>3)&3)<<3
//   (valid because staged row&7 == lane>>2 in all calls); read col
//   cs = quad*8 ^ ((l15>>1)&3)<<3.
// EPI=0: fused QKV epilogue with in-epilogue L2 norm (n-tile = one head).
// EPI=1: fp32 flat output + bias.
// ---------------------------------------------------------------------------
#define BUFE (384 * 32)   // elements per buffer: A 256x32 (8192) + B 128x32 (4096)

template <int EPI>
__global__ __launch_bounds__(256) void gemm4(
    const unsigned short* __restrict__ A, const unsigned short* __restrict__ Bw,
    const float* __restrict__ b0, const float* __restrict__ b1,
    const float* __restrict__ b2, const float* __restrict__ scale_p,
    void* __restrict__ Cp, int M, int N, int K)
{
    __shared__ __align__(16) unsigned short sBuf[3 * BUFE];   // 73728 B

    const int tid  = threadIdx.x;
    const int w    = tid >> 6, lane = tid & 63;     // 4 waves
    const int l15  = lane & 15, quad = lane >> 4;
    const int wr   = w >> 1, wc = w & 1;            // 2M x 2N waves
    const int tm   = blockIdx.y * 256, tn = blockIdx.x * 128;

    // staging source column (inverse swizzle) and read column (swizzle)
    const int colE = ((lane & 3) * 8) ^ (((lane >> 3) & 3) << 3);
    const int cs   = (quad * 8) ^ (((l15 >> 1) & 3) << 3);

    floatx4 acc[8][4] = {};

    auto stage = [&](int kt, int bsel) {
        const int k0 = kt * 32;
        unsigned short* bb = &sBuf[bsel * BUFE];
#pragma unroll
        for (int j = 0; j < 4; j++)   // A-tile 256x32: 4 calls/wave
            glds16(bb + w * 2048 + j * 512,
                   &A[(size_t)(tm + w * 64 + j * 16 + (lane >> 2)) * K + k0 + colE]);
#pragma unroll
        for (int j = 0; j < 2; j++)   // B-tile 128x32: 2 calls/wave
            glds16(bb + 8192 + w * 1024 + j * 512,
                   &Bw[(size_t)(tn + w * 32 + j * 16 + (lane >> 2)) * K + k0 + colE]);
    };

    const int nT = K >> 5;            // 64 K-tiles
    stage(0, 0);
    stage(1, 1);

    int bs = 0;
    for (int t = 0; t < nT; ++t) {
        if (t < nT - 1) asm volatile("s_waitcnt vmcnt(6)" ::: "memory");
        else            asm volatile("s_waitcnt vmcnt(0)" ::: "memory");
        __builtin_amdgcn_s_barrier();
        __builtin_amdgcn_sched_barrier(0);

        const unsigned short* bufA = &sBuf[bs * BUFE];
        const unsigned short* bufB = bufA + 8192;
        short8 af[8], bfr[4];
#pragma unroll
        for (int ni = 0; ni < 4; ni++)
            bfr[ni] = *(const short8*)&bufB[(wc * 64 + ni * 16 + l15) * 32 + cs];
#pragma unroll
        for (int mi = 0; mi < 8; mi++)
            af[mi] = *(const short8*)&bufA[(wr * 128 + mi * 16 + l15) * 32 + cs];

        if (t + 2 < nT) stage(t + 2, bs == 0 ? 2 : bs - 1);

        __builtin_amdgcn_s_setprio(1);
#pragma unroll
        for (int mi = 0; mi < 8; mi++)
#pragma unroll
            for (int ni = 0; ni < 4; ni++)
                acc[mi][ni] = __builtin_amdgcn_mfma_f32_16x16x32_bf16(af[mi], bfr[ni], acc[mi][ni], 0, 0, 0);
        __builtin_amdgcn_s_setprio(0);

        bs = (bs == 2) ? 0 : bs + 1;
    }
    __syncthreads();   // loop done, nothing outstanding; safe full drain

    // Epilogue: C/D layout row = quad*4 + r, col = l15 (m89-verified)
    if (EPI == 0) {
        const int t = tn >> 11;
        const float* bp = (t == 0) ? b0 : (t == 1) ? b1 : b2;
        unsigned short* Q = (unsigned short*)Cp;
        // bias first (reference normalizes x@W.T + b)
#pragma unroll
        for (int ni = 0; ni < 4; ni++) {
            int n = tn + wc * 64 + ni * 16 + l15;
            float bias = bp[n & 2047];
#pragma unroll
            for (int mi = 0; mi < 8; mi++)
#pragma unroll
                for (int r = 0; r < 4; r++) acc[mi][ni][r] += bias;
        }
        // per-row sum of squares over this wave's 64-dh half
        float ssq[8][4];
#pragma unroll
        for (int mi = 0; mi < 8; mi++)
#pragma unroll
            for (int r = 0; r < 4; r++) {
                float s = 0.0f;
#pragma unroll
                for (int ni = 0; ni < 4; ni++) s += acc[mi][ni][r] * acc[mi][ni][r];
#pragma unroll
                for (int off = 1; off < 16; off <<= 1) s += __shfl_xor(s, off, 64);
                ssq[mi][r] = s;
            }
        float* ssh = (float*)sBuf;      // 512 floats, reuse sBuf
        if (l15 == 0) {
#pragma unroll
            for (int mi = 0; mi < 8; mi++)
#pragma unroll
                for (int r = 0; r < 4; r++)
                    ssh[wc * 256 + wr * 128 + mi * 16 + quad * 4 + r] = ssq[mi][r];
        }
        __syncthreads();
        const float scl = (t == 0) ? scale_p[0] : 1.0f;
#pragma unroll
        for (int mi = 0; mi < 8; mi++) {
            int mbase = tm + wr * 128 + mi * 16 + quad * 4;
#pragma unroll
            for (int r = 0; r < 4; r++) {
                float tot = ssq[mi][r] + ssh[(wc ^ 1) * 256 + wr * 128 + mi * 16 + quad * 4 + r];
                float f = (t < 2) ? rsqrtf(tot) * scl : 1.0f;
                int m = mbase + r;
                int b = m >> 11, s = m & 2047;
#pragma unroll
                for (int ni = 0; ni < 4; ni++) {
                    int n = tn + wc * 64 + ni * 16 + l15;
                    int h = (n >> 7) & 15, dh = n & 127;
                    float v = acc[mi][ni][r] * f;
                    size_t idx = (t < 2)
                        ? (size_t)t * SEGQ + (((size_t)(b * NHEAD + h)) * S_LEN + s) * DHEAD + dh
                        : 2 * SEGQ + (((size_t)(b * NHEAD + h)) * DHEAD + dh) * S_LEN + s;
                    Q[idx] = f2bf(v);
                }
            }
        }
    } else {
#pragma unroll
        for (int mi = 0; mi < 8; mi++) {
            int mbase = tm + wr * 128 + mi * 16 + quad * 4;
#pragma unroll
            for (int ni = 0; ni < 4; ni++) {
                int n = tn + wc * 64 + ni * 16 + l15;
                float bias = b0[n];
#pragma unroll
                for (int r = 0; r < 4; r++) {
                    int m = mbase + r;
                    ((float*)Cp)[(size_t)m * N + n] = acc[mi][ni][r] + bias;
                }
            }
        }
    }
}

// ---------------------------------------------------------------------------
// Fallback GEMM (R3-proven): fp32 A/B converted during staging.
// SPLIT: 0 none, 1 (b,h,s,dh), 2 transposed V (b,h,dh,s).
// ---------------------------------------------------------------------------
template <int SPLIT, int A_F32, int OUT_F32>
__global__ __launch_bounds__(256) void gemm_bt(
    const void* __restrict__ Ap, const float* __restrict__ Bw,
    const float* __restrict__ bias, void* __restrict__ Cp,
    int M, int N, int K)
{
    __shared__ __align__(16) unsigned short sA[128 * 40];
    __shared__ __align__(16) unsigned short sB[128 * 40];

    const int tid  = threadIdx.x;
    const int w    = tid >> 6, lane = tid & 63;
    const int l15  = lane & 15, quad = lane >> 4;
    const int wm   = w >> 1, wn = w & 1;
    const int tm   = blockIdx.y * 128, tn = blockIdx.x * 128;

    const float*          Af32 = (const float*)Ap;
    const unsigned short* Abf  = (const unsigned short*)Ap;

    floatx4 acc[4][4] = {};

    for (int k0 = 0; k0 < K; k0 += 32) {
        __syncthreads();
#pragma unroll
        for (int i = 0; i < 2; i++) {
            int c   = tid + i * 256;
            int row = c >> 2;
            int kc  = (c & 3) * 8;
            size_t goff = (size_t)(tm + row) * K + k0 + kc;
            if (A_F32)
                *(short8*)&sA[row * 40 + kc] = ld8_f32_as_bf16(&Af32[goff]);
            else
                *(short8*)&sA[row * 40 + kc] = *(const short8*)&Abf[goff];
            *(short8*)&sB[row * 40 + kc] =
                ld8_f32_as_bf16(&Bw[(size_t)(tn + row) * K + k0 + kc]);
        }
        __syncthreads();

        short8 af[4], bfr[4];
#pragma unroll
        for (int mi = 0; mi < 4; mi++)
            af[mi] = *(const short8*)&sA[(wm * 64 + mi * 16 + l15) * 40 + quad * 8];
#pragma unroll
        for (int ni = 0; ni < 4; ni++)
            bfr[ni] = *(const short8*)&sB[(wn * 64 + ni * 16 + l15) * 40 + quad * 8];
#pragma unroll
        for (int mi = 0; mi < 4; mi++)
#pragma unroll
            for (int ni = 0; ni < 4; ni++)
                acc[mi][ni] = __builtin_amdgcn_mfma_f32_16x16x32_bf16(af[mi], bfr[ni], acc[mi][ni], 0, 0, 0);
    }

#pragma unroll
    for (int mi = 0; mi < 4; mi++) {
        int mbase = tm + wm * 64 + mi * 16 + quad * 4;
#pragma unroll
        for (int ni = 0; ni < 4; ni++) {
            int n = tn + wn * 64 + ni * 16 + l15;
            float bv = bias[n];
#pragma unroll
            for (int r = 0; r < 4; r++) {
                int m = mbase + r;
                float v = acc[mi][ni][r] + bv;
                if (SPLIT == 1) {
                    int b = m >> 11, s = m & 2047, h = n >> 7, dh = n & 127;
                    ((unsigned short*)Cp)[(((size_t)(b * NHEAD + h)) * S_LEN + s) * DHEAD + dh] = f2bf(v);
                } else if (SPLIT == 2) {
                    int b = m >> 11, s = m & 2047, h = n >> 7, dh = n & 127;
                    ((unsigned short*)Cp)[(((size_t)(b * NHEAD + h)) * DHEAD + dh) * S_LEN + s] = f2bf(v);
                } else if (OUT_F32) {
                    ((float*)Cp)[(size_t)m * N + n] = v;
                } else {
                    ((unsigned short*)Cp)[(size_t)m * N + n] = f2bf(v);
                }
            }
        }
    }
}

// ---------------------------------------------------------------------------
// Fallback-path L2 norm (fast path fuses it into the QKV epilogue).
// ---------------------------------------------------------------------------
__global__ __launch_bounds__(256) void l2norm_kernel(
    unsigned short* __restrict__ qn, unsigned short* __restrict__ kn,
    const float* __restrict__ scale_p)
{
    const int w = threadIdx.x >> 6, lane = threadIdx.x & 63;
    size_t row = (size_t)blockIdx.x * 4 + w;
    unsigned short* base = (blockIdx.y == 0 ? qn : kn) + row * DHEAD;
    float a = bf2f(base[lane * 2]);
    float b = bf2f(base[lane * 2 + 1]);
    float ss = a * a + b * b;
#pragma unroll
    for (int off = 1; off < 64; off <<= 1) ss += __shfl_xor(ss, off, 64);
    float f = rsqrtf(ss);
    if (blockIdx.y == 0) f *= scale_p[0];
    base[lane * 2]     = f2bf(a * f);
    base[lane * 2 + 1] = f2bf(b * f);
}

// ---------------------------------------------------------------------------
// Flash attention v4: 128x128 tiles, 8-wave (512-thr) blocks, grid (8,32).
// Block x handles Q-tiles {x, 15-x} -> exactly 17 kt-iterations at 2x MFMA
// per iteration. K staged once per block (shared by 8 waves); V arrives
// pre-transposed; 1-deep register prefetch.
// LDS: 3 x 34816 B = 102 KiB of the 160 KiB/CU -> 1 block/CU.
// ---------------------------------------------------------------------------
#define KSTR  136   // 272B rows: 16B-aligned, 2-way banks (free per m136)
#define VTSTR 136
#define PSTR  136

__global__ __launch_bounds__(512) void attn_kernel4(
    const unsigned short* __restrict__ qn, const unsigned short* __restrict__ kn,
    const unsigned short* __restrict__ vt, unsigned short* __restrict__ ctx)
{
    __shared__ __align__(16) unsigned short sK [128 * KSTR];
    __shared__ __align__(16) unsigned short sVt[128 * VTSTR];
    __shared__ __align__(16) unsigned short sP [8 * 16 * PSTR];

    const int tid  = threadIdx.x;
    const int w    = tid >> 6, lane = tid & 63;   // w in [0,8)
    const int l15  = lane & 15, quad = lane >> 4;
    const int xb   = blockIdx.x, bh = blockIdx.y;
    const size_t headoff = (size_t)bh * S_LEN * DHEAD;
    const unsigned short* kbase0 = kn + headoff;
    const unsigned short* vtbase = vt + headoff;   // [dh][s] within head
    unsigned short* sPw = sP + w * 16 * PSTR;

    short8 kpre[4], vpre[4];

    for (int half = 0; half < 2; half++) {
        const int qt = half ? (15 - xb) : xb;      // 128-row Q tiles

        const unsigned short* qrow = qn + headoff + (size_t)(qt * 128 + w * 16 + l15) * DHEAD;
        short8 aQ[4];
#pragma unroll
        for (int ks = 0; ks < 4; ks++) aQ[ks] = *(const short8*)(qrow + ks * 32 + quad * 8);

        floatx4 O[8] = {};
        float m_i[4], l_i[4];
#pragma unroll
        for (int r = 0; r < 4; r++) { m_i[r] = -1e30f; l_i[r] = 0.0f; }

        if (half == 0) {  // prefetch kt=0 (half 1 gets it from half 0's tail)
#pragma unroll
            for (int j = 0; j < 4; j++) {
                int c = tid + j * 512;   // 128x128 tile = 2048 16B chunks
                kpre[j] = *(const short8*)(kbase0 + (size_t)(c >> 4) * DHEAD + (c & 15) * 8);
                vpre[j] = *(const short8*)(vtbase + (size_t)(c >> 4) * S_LEN + (c & 15) * 8);
            }
        }

        for (int kt = 0; kt <= qt; kt++) {
            __syncthreads();   // previous iteration's LDS reads complete (WAR)

            // Commit prefetched K-tile and V^T-tile (all ds_write_b128)
#pragma unroll
            for (int j = 0; j < 4; j++) {
                int c = tid + j * 512;
                *(short8*)&sK [(c >> 4) * KSTR  + (c & 15) * 8] = kpre[j];
                *(short8*)&sVt[(c >> 4) * VTSTR + (c & 15) * 8] = vpre[j];
            }

            // Prefetch next tile (next kt, or kt=0 for the second Q-tile)
            if (kt < qt || half == 0) {
                const int knext = (kt < qt) ? (kt + 1) * 128 : 0;
#pragma unroll
                for (int j = 0; j < 4; j++) {
                    int c = tid + j * 512;
                    kpre[j] = *(const short8*)(kbase0 + (size_t)(knext + (c >> 4)) * DHEAD + (c & 15) * 8);
                    vpre[j] = *(const short8*)(vtbase + (size_t)(c >> 4) * S_LEN + knext + (c & 15) * 8);
                }
            }
            __syncthreads();

            // S = Q K^T (wave strip 16 x 128)
            floatx4 sc[8] = {};
#pragma unroll
            for (int ks = 0; ks < 4; ks++) {
#pragma unroll
                for (int ni = 0; ni < 8; ni++) {
                    short8 bK = *(const short8*)&sK[(ni * 16 + l15) * KSTR + ks * 32 + quad * 8];
                    sc[ni] = __builtin_amdgcn_mfma_f32_16x16x32_bf16(aQ[ks], bK, sc[ni], 0, 0, 0);
                }
            }

            if (kt == qt) {  // causal mask within diagonal tile
#pragma unroll
                for (int ni = 0; ni < 8; ni++) {
                    int cl = ni * 16 + l15;
#pragma unroll
                    for (int r = 0; r < 4; r++) {
                        int rl = w * 16 + quad * 4 + r;
                        if (cl > rl) sc[ni][r] = -1e30f;
                    }
                }
            }

            // Online softmax (stats replicated across the 16 lanes of a quad)
            float rmax[4];
#pragma unroll
            for (int r = 0; r < 4; r++) {
                float mx = sc[0][r];
#pragma unroll
                for (int ni = 1; ni < 8; ni++) mx = fmaxf(mx, sc[ni][r]);
                rmax[r] = mx;
            }
#pragma unroll
            for (int off = 1; off < 16; off <<= 1)
#pragma unroll
                for (int r = 0; r < 4; r++) rmax[r] = fmaxf(rmax[r], __shfl_xor(rmax[r], off, 64));

            float alpha[4], rsum[4];
#pragma unroll
            for (int r = 0; r < 4; r++) {
                float mn = fmaxf(m_i[r], rmax[r]);
                alpha[r] = exp2f((m_i[r] - mn) * 1.44269504f);
                m_i[r] = mn;
                rsum[r] = 0.0f;
            }
#pragma unroll
            for (int ni = 0; ni < 8; ni++) {
#pragma unroll
                for (int r = 0; r < 4; r++) {
                    float p = exp2f((sc[ni][r] - m_i[r]) * 1.44269504f);
                    rsum[r] += p;
                    sPw[(quad * 4 + r) * PSTR + ni * 16 + l15] = f2bf(p);
                }
            }
#pragma unroll
            for (int off = 1; off < 16; off <<= 1)
#pragma unroll
                for (int r = 0; r < 4; r++) rsum[r] += __shfl_xor(rsum[r], off, 64);
#pragma unroll
            for (int r = 0; r < 4; r++) l_i[r] = l_i[r] * alpha[r] + rsum[r];
#pragma unroll
            for (int t = 0; t < 8; t++)
#pragma unroll
                for (int r = 0; r < 4; r++) O[t][r] *= alpha[r];

            __syncthreads();  // order P ds_writes before ds_reads below

            // O += P V   (k-dim = 128 keys)
#pragma unroll
            for (int ks2 = 0; ks2 < 4; ks2++) {
                short8 aP = *(const short8*)&sPw[l15 * PSTR + ks2 * 32 + quad * 8];
#pragma unroll
                for (int t = 0; t < 8; t++) {
                    short8 bV = *(const short8*)&sVt[(t * 16 + l15) * VTSTR + ks2 * 32 + quad * 8];
                    O[t] = __builtin_amdgcn_mfma_f32_16x16x32_bf16(aP, bV, O[t], 0, 0, 0);
                }
            }
        }

        // Epilogue: ctx[b, s, h*128 + dh] = O / l
        const int b = bh >> 4, h = bh & 15;
#pragma unroll
        for (int r = 0; r < 4; r++) {
            float inv = 1.0f / l_i[r];
            int srow = qt * 128 + w * 16 + quad * 4 + r;
            size_t rowoff = ((size_t)(b * S_LEN + srow)) * DIMN + h * DHEAD;
#pragma unroll
            for (int t = 0; t < 8; t++)
                ctx[rowoff + t * 16 + l15] = f2bf(O[t][r] * inv);
        }
    }
}

// ---------------------------------------------------------------------------
extern "C" void kernel_launch(void* const* d_in, const int* in_sizes, int n_in,
                              void* d_out, int out_size, void* d_ws, size_t ws_size,
                              hipStream_t stream)
{
    const float* x     = (const float*)d_in[0];
    // d_in[1] = causal mask (bool) — deterministic tril, masking hard-coded
    const float* Wq    = (const float*)d_in[2];
    const float* bq    = (const float*)d_in[3];
    const float* Wk    = (const float*)d_in[4];
    const float* bk    = (const float*)d_in[5];
    const float* Wv    = (const float*)d_in[6];
    const float* bv    = (const float*)d_in[7];
    const float* Wo    = (const float*)d_in[8];
    const float* bo    = (const float*)d_in[9];
    const float* scale = (const float*)d_in[10];

    const int M = 4096, N = 2048, K = 2048;
    float* out = (float*)d_out;
    const size_t need = (SEGQ + 4 * SEGW + 3 * SEGQ) * sizeof(unsigned short); // 100.7 MB

    if (ws_size >= need) {
        // Fast path: bf16 operands; pipelined fused QKV GEMM (+L2 norm).
        unsigned short* xb  = (unsigned short*)d_ws;   // ctx aliases xb (dead after QKV)
        unsigned short* wqb = xb  + SEGQ;              // wqb|wkb|wvb contiguous = fused B
        unsigned short* wkb = wqb + SEGW;
        unsigned short* wvb = wkb + SEGW;
        unsigned short* wob = wvb + SEGW;
        unsigned short* qn  = wob + SEGW;              // qn|kn|vt contiguous
        unsigned short* kn  = qn  + SEGQ;
        unsigned short* vtb = kn  + SEGQ;
        unsigned short* ctx = xb;

        cvt5_kernel<<<dim3(512, 5), 256, 0, stream>>>(x, Wq, Wk, Wv, Wo,
                                                      xb, wqb, wkb, wvb, wob);
        gemm4<0><<<dim3(48, 16), 256, 0, stream>>>(xb, wqb, bq, bk, bv, scale, qn, M, 6144, K);
        attn_kernel4<<<dim3(8, 32), 512, 0, stream>>>(qn, kn, vtb, ctx);
        gemm4<1><<<dim3(16, 16), 256, 0, stream>>>(ctx, wob, bo, nullptr, nullptr, nullptr, out, M, N, K);
    } else {
        // Fallback (67 MB): fp32 operands converted during staging.
        unsigned short* qn  = (unsigned short*)d_ws;
        unsigned short* kn  = qn + SEGQ;
        unsigned short* vtb = kn + SEGQ;
        unsigned short* ctx = vtb + SEGQ;

        gemm_bt<1, 1, 0><<<dim3(16, 32), 256, 0, stream>>>(x, Wq, bq, qn, M, N, K);
        gemm_bt<1, 1, 0><<<dim3(16, 32), 256, 0, stream>>>(x, Wk, bk, kn, M, N, K);
        gemm_bt<2, 1, 0><<<dim3(16, 32), 256, 0, stream>>>(x, Wv, bv, vtb, M, N, K);
        l2norm_kernel<<<dim3(16384, 2), 256, 0, stream>>>(qn, kn, scale);
        attn_kernel4<<<dim3(8, 32), 512, 0, stream>>>(qn, kn, vtb, ctx);
        gemm_bt<0, 0, 1><<<dim3(16, 32), 256, 0, stream>>>(ctx, Wo, bo, out, M, N, K);
    }
}

// Round 5
// 435.831 us; speedup vs baseline: 1.0275x; 1.0275x over previous
//
#include <hip/hip_runtime.h>
#include <hip/hip_bf16.h>

// Problem constants (BS=2, SLEN=2048, DIM=2048, H=16, DH=128)
// I/O dtype: fp32. Internals: bf16 MFMA, fp32 accumulation, bf16 workspace.
#define S_LEN 2048
#define DIMN  2048
#define NHEAD 16
#define DHEAD 128
#define SEGQ  ((size_t)4096 * 2048)
#define SEGW  ((size_t)2048 * 2048)

typedef __attribute__((ext_vector_type(8))) short short8;
typedef __attribute__((ext_vector_type(4))) float floatx4;

__device__ inline float bf2f(unsigned short u) {
    union { unsigned int i; float f; } v; v.i = ((unsigned int)u) << 16; return v.f;
}
__device__ inline unsigned short f2bf(float f) {
    unsigned int x = __float_as_uint(f);
    unsigned int r = (x + 0x7FFFu + ((x >> 16) & 1u)) >> 16;  // RNE
    return (unsigned short)r;
}
__device__ inline short8 ld8_f32_as_bf16(const float* p) {
    float4 a = *(const float4*)p;
    float4 b = *(const float4*)(p + 4);
    short8 r;
    r[0] = (short)f2bf(a.x); r[1] = (short)f2bf(a.y);
    r[2] = (short)f2bf(a.z); r[3] = (short)f2bf(a.w);
    r[4] = (short)f2bf(b.x); r[5] = (short)f2bf(b.y);
    r[6] = (short)f2bf(b.z); r[7] = (short)f2bf(b.w);
    return r;
}
// Async global->LDS, 16B/lane; LDS base wave-uniform, lane i at +i*16.
__device__ inline void glds16(unsigned short* lds, const unsigned short* g) {
    __builtin_amdgcn_global_load_lds(
        (const __attribute__((address_space(1))) unsigned int*)g,
        (__attribute__((address_space(3))) unsigned int*)lds, 16, 0, 0);
}

#define BARX()  do { __builtin_amdgcn_s_barrier(); __builtin_amdgcn_sched_barrier(0); } while (0)
#define LGKM0() do { asm volatile("s_waitcnt lgkmcnt(0)" ::: "memory"); __builtin_amdgcn_sched_barrier(0); } while (0)

// ---------------------------------------------------------------------------
// One-shot fp32 -> bf16 conversion of x, Wq, Wk, Wv, Wo (blockIdx.y selects).
// ---------------------------------------------------------------------------
__global__ __launch_bounds__(256) void cvt5_kernel(
    const float* __restrict__ s0, const float* __restrict__ s1,
    const float* __restrict__ s2, const float* __restrict__ s3,
    const float* __restrict__ s4,
    unsigned short* __restrict__ d0, unsigned short* __restrict__ d1,
    unsigned short* __restrict__ d2, unsigned short* __restrict__ d3,
    unsigned short* __restrict__ d4)
{
    const float* s; unsigned short* d; size_t n;
    switch (blockIdx.y) {
        case 0:  s = s0; d = d0; n = SEGQ; break;
        case 1:  s = s1; d = d1; n = SEGW; break;
        case 2:  s = s2; d = d2; n = SEGW; break;
        case 3:  s = s3; d = d3; n = SEGW; break;
        default: s = s4; d = d4; n = SEGW; break;
    }
    size_t stride = (size_t)gridDim.x * 256 * 8;
    for (size_t i = ((size_t)blockIdx.x * 256 + threadIdx.x) * 8; i < n; i += stride)
        *(short8*)&d[i] = ld8_f32_as_bf16(&s[i]);
}

// ---------------------------------------------------------------------------
// gemm8: m201-style 8-phase 256x256 bf16 GEMM (QKV only; fused L2-norm epi).
//   BK=64, 512 thr = 8 waves (2M x 4N), wave tile 128x64. LDS = 2 K-tile
//   buffers x (A 256x64 + B 256x64) bf16 = 128 KB -> 1 block/CU.
//   Per K-tile: 4 phases = C-quadrants in order (qm,qn) = (0,0)(0,1)(1,1)(1,0)
//   -> per-phase ds_reads 12/4/8/0, 16 MFMA each (m x n x s = 4x2x2).
//   Staging unit = 128 rows of A or B (16 KB = 2 glds16/wave). Dead-slot
//   schedule (iter computes t@buf0, t+1@buf1; units dead after their last
//   read phase, stage strictly after):
//     p1: A1[b1]<-t+1 (pending from prev iter; dead since prev p7)
//     p3: B0[b0]<-t+2 (B units of buf0 dead after p2)
//     p4: B1[b0]<-t+2
//     p5: A0[b0]<-t+2 (A units of buf0 dead after p3)
//     p6: A1[b0]<-t+2
//     p7: B0[b1]<-t+3 (B units of buf1 dead after p6)
//     p8: B1[b1]+A0[b1]<-t+3 (A units of buf1 dead after p7)
//   RAW guards, once per K-tile, BEFORE the phase-closing barrier so every
//   wave's loads are proven landed when any wave proceeds:
//     p4: vmcnt(4)  (allow p3+p4 = 4 younger; buf1 = t+1 fully landed)
//     p8: vmcnt(6)  (allow p7+p8 = 6 younger; buf0 = t+2 fully landed)
//   Tail (last iter): p4 uses vmcnt(0), staging conditionals skip, final
//   __syncthreads drains. Swizzle (both-sides involution, rule #21):
//   LDS[row][c] = G[row][c ^ S(row)], S(row) = ((row>>1)&7)<<3 elems ->
//   16-lane fragment reads spread over 8 16B slots (2-way banks, free).
//   glds source col: colE = (lane&7)*8 ^ ((4*(w&1) | (lane>>4))<<3);
//   ds_read col: cs = (s*32 + quad*8) ^ ((l15>>1&7)<<3).
// ---------------------------------------------------------------------------
__global__ __launch_bounds__(512) void gemm8(
    const unsigned short* __restrict__ A, const unsigned short* __restrict__ Bw,
    const float* __restrict__ b0, const float* __restrict__ b1,
    const float* __restrict__ b2, const float* __restrict__ scale_p,
    unsigned short* __restrict__ Cp, int M, int N, int K)
{
    __shared__ __align__(16) unsigned short sA[2][256 * 64];   // 64 KB
    __shared__ __align__(16) unsigned short sB[2][256 * 64];   // 64 KB

    const int tid  = threadIdx.x;
    const int w    = tid >> 6, lane = tid & 63;
    const int l15  = lane & 15, quad = (lane >> 4) & 3;
    const int wr   = w >> 2, wc = w & 3;            // 2M x 4N waves
    const int tm   = blockIdx.y * 256, tn = blockIdx.x * 256;

    const int colE = ((lane & 7) * 8) ^ (((4 * (w & 1)) | (lane >> 4)) << 3);
    const int swzr = ((l15 >> 1) & 7) << 3;
    const int cs0  = (quad * 8) ^ swzr;
    const int cs1  = (32 + quad * 8) ^ swzr;

    const unsigned short* Ag = A  + (size_t)tm * K;
    const unsigned short* Bg = Bw + (size_t)tn * K;

    floatx4 acc[8][4] = {};
    short8 aF[4][2], bF0[2][2], bF1[2][2];

    auto stA = [&](int kt, int half, int buf) {
#pragma unroll
        for (int j = 0; j < 2; j++) {
            int r0 = half * 128 + j * 64 + w * 8;
            glds16(&sA[buf][r0 * 64], &Ag[(size_t)(r0 + (lane >> 3)) * K + kt * 64 + colE]);
        }
    };
    auto stB = [&](int kt, int half, int buf) {
#pragma unroll
        for (int j = 0; j < 2; j++) {
            int r0 = half * 128 + j * 64 + w * 8;
            glds16(&sB[buf][r0 * 64], &Bg[(size_t)(r0 + (lane >> 3)) * K + kt * 64 + colE]);
        }
    };
    auto ldA = [&](int buf, int qm) {
#pragma unroll
        for (int m = 0; m < 4; m++) {
            int r = (wr * 128 + qm * 64 + m * 16 + l15) * 64;
            aF[m][0] = *(const short8*)&sA[buf][r + cs0];
            aF[m][1] = *(const short8*)&sA[buf][r + cs1];
        }
    };
    auto ldB0 = [&](int buf) {
#pragma unroll
        for (int n = 0; n < 2; n++) {
            int r = (wc * 64 + n * 16 + l15) * 64;
            bF0[n][0] = *(const short8*)&sB[buf][r + cs0];
            bF0[n][1] = *(const short8*)&sB[buf][r + cs1];
        }
    };
    auto ldB1 = [&](int buf) {
#pragma unroll
        for (int n = 0; n < 2; n++) {
            int r = (wc * 64 + 32 + n * 16 + l15) * 64;
            bF1[n][0] = *(const short8*)&sB[buf][r + cs0];
            bF1[n][1] = *(const short8*)&sB[buf][r + cs1];
        }
    };
    auto mf = [&](int qm, const short8 (&bf)[2][2], int qn) {
        __builtin_amdgcn_s_setprio(1);
#pragma unroll
        for (int m = 0; m < 4; m++)
#pragma unroll
            for (int n = 0; n < 2; n++) {
                acc[qm * 4 + m][qn * 2 + n] = __builtin_amdgcn_mfma_f32_16x16x32_bf16(
                    aF[m][0], bf[n][0], acc[qm * 4 + m][qn * 2 + n], 0, 0, 0);
                acc[qm * 4 + m][qn * 2 + n] = __builtin_amdgcn_mfma_f32_16x16x32_bf16(
                    aF[m][1], bf[n][1], acc[qm * 4 + m][qn * 2 + n], 0, 0, 0);
            }
        __builtin_amdgcn_s_setprio(0);
    };

    // Prologue: per-wave issue order matches steady-state vmcnt counting.
    stB(0, 0, 0); stB(0, 1, 0); stA(0, 0, 0); stA(0, 1, 0);
    stB(1, 0, 1); stB(1, 1, 1); stA(1, 0, 1);
    asm volatile("s_waitcnt vmcnt(6)" ::: "memory");   // buf0 (8 loads) landed
    BARX();

    const int nIter = K >> 7;                          // 16 (2 K-tiles/iter)
    for (int it = 0; it < nIter; ++it) {
        const int t2 = 2 * it + 2, t3 = 2 * it + 3;
        const bool s2 = (t2 < (K >> 6));               // stage t+2?
        const bool s3 = (t3 < (K >> 6));               // stage t+3?
        // ---- p1 (0,0) @buf0
        ldA(0, 0); ldB0(0);
        stA(2 * it + 1, 1, 1);                         // A1[b1] <- t+1 (always valid)
        BARX(); LGKM0();
        mf(0, bF0, 0);
        BARX();
        // ---- p2 (0,1)
        ldB1(0);
        BARX(); LGKM0();
        mf(0, bF1, 1);
        BARX();
        // ---- p3 (1,1)
        ldA(0, 1);
        if (s2) stB(t2, 0, 0);
        BARX(); LGKM0();
        mf(1, bF1, 1);
        BARX();
        // ---- p4 (1,0)  + K-tile guard for buf1
        if (s2) stB(t2, 1, 0);
        BARX(); LGKM0();
        mf(1, bF0, 0);
        if (s2) { asm volatile("s_waitcnt vmcnt(4)" ::: "memory"); }
        else    { asm volatile("s_waitcnt vmcnt(0)" ::: "memory"); }
        BARX();
        // ---- p5 (0,0) @buf1
        ldA(1, 0); ldB0(1);
        if (s2) stA(t2, 0, 0);
        BARX(); LGKM0();
        mf(0, bF0, 0);
        BARX();
        // ---- p6 (0,1)
        ldB1(1);
        if (s2) stA(t2, 1, 0);
        BARX(); LGKM0();
        mf(0, bF1, 1);
        BARX();
        // ---- p7 (1,1)
        ldA(1, 1);
        if (s3) stB(t3, 0, 1);
        BARX(); LGKM0();
        mf(1, bF1, 1);
        BARX();
        // ---- p8 (1,0)  + K-tile guard for buf0
        if (s3) { stB(t3, 1, 1); stA(t3, 0, 1); }
        BARX(); LGKM0();
        mf(1, bF0, 0);
        if (s3) { asm volatile("s_waitcnt vmcnt(6)" ::: "memory"); }
        BARX();
    }
    __syncthreads();   // full drain before LDS reuse

    // ---- Fused QKV epilogue with in-epilogue L2 norm over dh=128 ----
    // C/D layout: row = quad*4 + r, col = l15 (m89-verified).
    // n-tile (256) spans 2 heads; norm partner wave = w^1 (wc 0<->1, 2<->3).
    const int t = tn >> 11;                       // 0=Q 1=K 2=V
    const float* bp = (t == 0) ? b0 : (t == 1) ? b1 : b2;
#pragma unroll
    for (int ni = 0; ni < 4; ni++) {
        int n = tn + wc * 64 + ni * 16 + l15;
        float bias = bp[n & 2047];
#pragma unroll
        for (int mi = 0; mi < 8; mi++)
#pragma unroll
            for (int r = 0; r < 4; r++) acc[mi][ni][r] += bias;
    }
    float ssq[8][4];
#pragma unroll
    for (int mi = 0; mi < 8; mi++)
#pragma unroll
        for (int r = 0; r < 4; r++) {
            float s = 0.0f;
#pragma unroll
            for (int ni = 0; ni < 4; ni++) s += acc[mi][ni][r] * acc[mi][ni][r];
#pragma unroll
            for (int off = 1; off < 16; off <<= 1) s += __shfl_xor(s, off, 64);
            ssq[mi][r] = s;
        }
    float* ssh = (float*)&sA[0][0];               // [8][128] floats
    if (l15 == 0) {
#pragma unroll
        for (int mi = 0; mi < 8; mi++)
#pragma unroll
            for (int r = 0; r < 4; r++)
                ssh[w * 128 + mi * 16 + quad * 4 + r] = ssq[mi][r];
    }
    __syncthreads();
    const float scl = (t == 0) ? scale_p[0] : 1.0f;
#pragma unroll
    for (int mi = 0; mi < 8; mi++) {
        int mbase = tm + wr * 128 + mi * 16 + quad * 4;
#pragma unroll
        for (int r = 0; r < 4; r++) {
            float tot = ssq[mi][r] + ssh[(w ^ 1) * 128 + mi * 16 + quad * 4 + r];
            float f = (t < 2) ? rsqrtf(tot) * scl : 1.0f;
            int m = mbase + r;
            int b = m >> 11, s = m & 2047;
#pragma unroll
            for (int ni = 0; ni < 4; ni++) {
                int n = tn + wc * 64 + ni * 16 + l15;
                int h = (n >> 7) & 15, dh = n & 127;
                float v = acc[mi][ni][r] * f;
                size_t idx = (t < 2)
                    ? (size_t)t * SEGQ + (((size_t)(b * NHEAD + h)) * S_LEN + s) * DHEAD + dh
                    : 2 * SEGQ + (((size_t)(b * NHEAD + h)) * DHEAD + dh) * S_LEN + s;
                Cp[idx] = f2bf(v);
            }
        }
    }
}

// ---------------------------------------------------------------------------
// gemm3 (R2-verified, 141 us QKV-rate): counted-vmcnt 3-buffer pipeline.
//   BM=256, BN=128, BK=32, 512 thr = 8 waves (4M x 2N), 64x64/wave.
//   Used for the out-projection (N=2048 -> 256 blocks = full CU round).
// ---------------------------------------------------------------------------
#define BUFE (384 * 32)

template <int EPI>
__global__ __launch_bounds__(512) void gemm3(
    const unsigned short* __restrict__ A, const unsigned short* __restrict__ Bw,
    const float* __restrict__ b0, const float* __restrict__ b1,
    const float* __restrict__ b2, const float* __restrict__ scale_p,
    void* __restrict__ Cp, int M, int N, int K)
{
    __shared__ __align__(16) unsigned short sBuf[3 * BUFE];   // 73728 B

    const int tid  = threadIdx.x;
    const int w    = tid >> 6, lane = tid & 63;
    const int l15  = lane & 15, quad = lane >> 4;
    const int wr   = w >> 1, wc = w & 1;            // 4M x 2N waves
    const int tm   = blockIdx.y * 256, tn = blockIdx.x * 128;

    const int colE = ((lane & 3) * 8) ^ (((lane >> 3) & 3) << 3);
    const int cs   = (quad * 8) ^ (((l15 >> 1) & 3) << 3);
    const int srow = w * 16 + (lane >> 2);

    floatx4 acc[4][4] = {};

    auto stage = [&](int kt, int bsel) {
        const int k0 = kt * 32;
        glds16(&sBuf[bsel * BUFE + 0 * 4096 + w * 512],
               &A[(size_t)(tm + srow) * K + k0 + colE]);
        glds16(&sBuf[bsel * BUFE + 1 * 4096 + w * 512],
               &A[(size_t)(tm + 128 + srow) * K + k0 + colE]);
        glds16(&sBuf[bsel * BUFE + 8192 + w * 512],
               &Bw[(size_t)(tn + srow) * K + k0 + colE]);
    };

    const int nT = K >> 5;
    stage(0, 0);
    stage(1, 1);

    int bs = 0;
    for (int t = 0; t < nT; ++t) {
        if (t < nT - 1) asm volatile("s_waitcnt vmcnt(3)" ::: "memory");
        else            asm volatile("s_waitcnt vmcnt(0)" ::: "memory");
        __builtin_amdgcn_s_barrier();
        __builtin_amdgcn_sched_barrier(0);

        const unsigned short* bufA = &sBuf[bs * BUFE];
        const unsigned short* bufB = bufA + 8192;
        short8 af[4], bfr[4];
#pragma unroll
        for (int mi = 0; mi < 4; mi++)
            af[mi] = *(const short8*)&bufA[(wr * 64 + mi * 16 + l15) * 32 + cs];
#pragma unroll
        for (int ni = 0; ni < 4; ni++)
            bfr[ni] = *(const short8*)&bufB[(wc * 64 + ni * 16 + l15) * 32 + cs];

        if (t + 2 < nT) stage(t + 2, bs == 0 ? 2 : bs - 1);

        __builtin_amdgcn_s_setprio(1);
#pragma unroll
        for (int mi = 0; mi < 4; mi++)
#pragma unroll
            for (int ni = 0; ni < 4; ni++)
                acc[mi][ni] = __builtin_amdgcn_mfma_f32_16x16x32_bf16(af[mi], bfr[ni], acc[mi][ni], 0, 0, 0);
        __builtin_amdgcn_s_setprio(0);

        bs = (bs == 2) ? 0 : bs + 1;
    }
    __syncthreads();

    if (EPI == 0) {
        // (unused in this build)
    } else {
#pragma unroll
        for (int mi = 0; mi < 4; mi++) {
            int mbase = tm + wr * 64 + mi * 16 + quad * 4;
#pragma unroll
            for (int ni = 0; ni < 4; ni++) {
                int n = tn + wc * 64 + ni * 16 + l15;
                float bias = b0[n];
#pragma unroll
                for (int r = 0; r < 4; r++) {
                    int m = mbase + r;
                    ((float*)Cp)[(size_t)m * N + n] = acc[mi][ni][r] + bias;
                }
            }
        }
    }
}

// ---------------------------------------------------------------------------
// Fallback GEMM: fp32 A/B converted during staging.
// SPLIT: 0 none, 1 (b,h,s,dh), 2 transposed V (b,h,dh,s).
// ---------------------------------------------------------------------------
template <int SPLIT, int A_F32, int OUT_F32>
__global__ __launch_bounds__(256) void gemm_bt(
    const void* __restrict__ Ap, const float* __restrict__ Bw,
    const float* __restrict__ bias, void* __restrict__ Cp,
    int M, int N, int K)
{
    __shared__ __align__(16) unsigned short sA[128 * 40];
    __shared__ __align__(16) unsigned short sB[128 * 40];

    const int tid  = threadIdx.x;
    const int w    = tid >> 6, lane = tid & 63;
    const int l15  = lane & 15, quad = lane >> 4;
    const int wm   = w >> 1, wn = w & 1;
    const int tm   = blockIdx.y * 128, tn = blockIdx.x * 128;

    const float*          Af32 = (const float*)Ap;
    const unsigned short* Abf  = (const unsigned short*)Ap;

    floatx4 acc[4][4] = {};

    for (int k0 = 0; k0 < K; k0 += 32) {
        __syncthreads();
#pragma unroll
        for (int i = 0; i < 2; i++) {
            int c   = tid + i * 256;
            int row = c >> 2;
            int kc  = (c & 3) * 8;
            size_t goff = (size_t)(tm + row) * K + k0 + kc;
            if (A_F32)
                *(short8*)&sA[row * 40 + kc] = ld8_f32_as_bf16(&Af32[goff]);
            else
                *(short8*)&sA[row * 40 + kc] = *(const short8*)&Abf[goff];
            *(short8*)&sB[row * 40 + kc] =
                ld8_f32_as_bf16(&Bw[(size_t)(tn + row) * K + k0 + kc]);
        }
        __syncthreads();

        short8 af[4], bfr[4];
#pragma unroll
        for (int mi = 0; mi < 4; mi++)
            af[mi] = *(const short8*)&sA[(wm * 64 + mi * 16 + l15) * 40 + quad * 8];
#pragma unroll
        for (int ni = 0; ni < 4; ni++)
            bfr[ni] = *(const short8*)&sB[(wn * 64 + ni * 16 + l15) * 40 + quad * 8];
#pragma unroll
        for (int mi = 0; mi < 4; mi++)
#pragma unroll
            for (int ni = 0; ni < 4; ni++)
                acc[mi][ni] = __builtin_amdgcn_mfma_f32_16x16x32_bf16(af[mi], bfr[ni], acc[mi][ni], 0, 0, 0);
    }

#pragma unroll
    for (int mi = 0; mi < 4; mi++) {
        int mbase = tm + wm * 64 + mi * 16 + quad * 4;
#pragma unroll
        for (int ni = 0; ni < 4; ni++) {
            int n = tn + wn * 64 + ni * 16 + l15;
            float bv = bias[n];
#pragma unroll
            for (int r = 0; r < 4; r++) {
                int m = mbase + r;
                float v = acc[mi][ni][r] + bv;
                if (SPLIT == 1) {
                    int b = m >> 11, s = m & 2047, h = n >> 7, dh = n & 127;
                    ((unsigned short*)Cp)[(((size_t)(b * NHEAD + h)) * S_LEN + s) * DHEAD + dh] = f2bf(v);
                } else if (SPLIT == 2) {
                    int b = m >> 11, s = m & 2047, h = n >> 7, dh = n & 127;
                    ((unsigned short*)Cp)[(((size_t)(b * NHEAD + h)) * DHEAD + dh) * S_LEN + s] = f2bf(v);
                } else if (OUT_F32) {
                    ((float*)Cp)[(size_t)m * N + n] = v;
                } else {
                    ((unsigned short*)Cp)[(size_t)m * N + n] = f2bf(v);
                }
            }
        }
    }
}

// ---------------------------------------------------------------------------
// Fallback-path L2 norm (fast path fuses it into the QKV epilogue).
// ---------------------------------------------------------------------------
__global__ __launch_bounds__(256) void l2norm_kernel(
    unsigned short* __restrict__ qn, unsigned short* __restrict__ kn,
    const float* __restrict__ scale_p)
{
    const int w = threadIdx.x >> 6, lane = threadIdx.x & 63;
    size_t row = (size_t)blockIdx.x * 4 + w;
    unsigned short* base = (blockIdx.y == 0 ? qn : kn) + row * DHEAD;
    float a = bf2f(base[lane * 2]);
    float b = bf2f(base[lane * 2 + 1]);
    float ss = a * a + b * b;
#pragma unroll
    for (int off = 1; off < 64; off <<= 1) ss += __shfl_xor(ss, off, 64);
    float f = rsqrtf(ss);
    if (blockIdx.y == 0) f *= scale_p[0];
    base[lane * 2]     = f2bf(a * f);
    base[lane * 2 + 1] = f2bf(b * f);
}

// ---------------------------------------------------------------------------
// Flash attention v4 (unchanged this round): 128x128 tiles, 8-wave blocks,
// grid (8,32); block x handles Q-tiles {x, 15-x}. 1 block/CU (102 KiB LDS).
// ---------------------------------------------------------------------------
#define KSTR  136
#define VTSTR 136
#define PSTR  136

__global__ __launch_bounds__(512) void attn_kernel4(
    const unsigned short* __restrict__ qn, const unsigned short* __restrict__ kn,
    const unsigned short* __restrict__ vt, unsigned short* __restrict__ ctx)
{
    __shared__ __align__(16) unsigned short sK [128 * KSTR];
    __shared__ __align__(16) unsigned short sVt[128 * VTSTR];
    __shared__ __align__(16) unsigned short sP [8 * 16 * PSTR];

    const int tid  = threadIdx.x;
    const int w    = tid >> 6, lane = tid & 63;   // w in [0,8)
    const int l15  = lane & 15, quad = lane >> 4;
    const int xb   = blockIdx.x, bh = blockIdx.y;
    const size_t headoff = (size_t)bh * S_LEN * DHEAD;
    const unsigned short* kbase0 = kn + headoff;
    const unsigned short* vtbase = vt + headoff;   // [dh][s] within head
    unsigned short* sPw = sP + w * 16 * PSTR;

    short8 kpre[4], vpre[4];

    for (int half = 0; half < 2; half++) {
        const int qt = half ? (15 - xb) : xb;      // 128-row Q tiles

        const unsigned short* qrow = qn + headoff + (size_t)(qt * 128 + w * 16 + l15) * DHEAD;
        short8 aQ[4];
#pragma unroll
        for (int ks = 0; ks < 4; ks++) aQ[ks] = *(const short8*)(qrow + ks * 32 + quad * 8);

        floatx4 O[8] = {};
        float m_i[4], l_i[4];
#pragma unroll
        for (int r = 0; r < 4; r++) { m_i[r] = -1e30f; l_i[r] = 0.0f; }

        if (half == 0) {
#pragma unroll
            for (int j = 0; j < 4; j++) {
                int c = tid + j * 512;
                kpre[j] = *(const short8*)(kbase0 + (size_t)(c >> 4) * DHEAD + (c & 15) * 8);
                vpre[j] = *(const short8*)(vtbase + (size_t)(c >> 4) * S_LEN + (c & 15) * 8);
            }
        }

        for (int kt = 0; kt <= qt; kt++) {
            __syncthreads();

#pragma unroll
            for (int j = 0; j < 4; j++) {
                int c = tid + j * 512;
                *(short8*)&sK [(c >> 4) * KSTR  + (c & 15) * 8] = kpre[j];
                *(short8*)&sVt[(c >> 4) * VTSTR + (c & 15) * 8] = vpre[j];
            }

            if (kt < qt || half == 0) {
                const int knext = (kt < qt) ? (kt + 1) * 128 : 0;
#pragma unroll
                for (int j = 0; j < 4; j++) {
                    int c = tid + j * 512;
                    kpre[j] = *(const short8*)(kbase0 + (size_t)(knext + (c >> 4)) * DHEAD + (c & 15) * 8);
                    vpre[j] = *(const short8*)(vtbase + (size_t)(c >> 4) * S_LEN + knext + (c & 15) * 8);
                }
            }
            __syncthreads();

            floatx4 sc[8] = {};
#pragma unroll
            for (int ks = 0; ks < 4; ks++) {
#pragma unroll
                for (int ni = 0; ni < 8; ni++) {
                    short8 bK = *(const short8*)&sK[(ni * 16 + l15) * KSTR + ks * 32 + quad * 8];
                    sc[ni] = __builtin_amdgcn_mfma_f32_16x16x32_bf16(aQ[ks], bK, sc[ni], 0, 0, 0);
                }
            }

            if (kt == qt) {
#pragma unroll
                for (int ni = 0; ni < 8; ni++) {
                    int cl = ni * 16 + l15;
#pragma unroll
                    for (int r = 0; r < 4; r++) {
                        int rl = w * 16 + quad * 4 + r;
                        if (cl > rl) sc[ni][r] = -1e30f;
                    }
                }
            }

            float rmax[4];
#pragma unroll
            for (int r = 0; r < 4; r++) {
                float mx = sc[0][r];
#pragma unroll
                for (int ni = 1; ni < 8; ni++) mx = fmaxf(mx, sc[ni][r]);
                rmax[r] = mx;
            }
#pragma unroll
            for (int off = 1; off < 16; off <<= 1)
#pragma unroll
                for (int r = 0; r < 4; r++) rmax[r] = fmaxf(rmax[r], __shfl_xor(rmax[r], off, 64));

            float alpha[4], rsum[4];
#pragma unroll
            for (int r = 0; r < 4; r++) {
                float mn = fmaxf(m_i[r], rmax[r]);
                alpha[r] = exp2f((m_i[r] - mn) * 1.44269504f);
                m_i[r] = mn;
                rsum[r] = 0.0f;
            }
#pragma unroll
            for (int ni = 0; ni < 8; ni++) {
#pragma unroll
                for (int r = 0; r < 4; r++) {
                    float p = exp2f((sc[ni][r] - m_i[r]) * 1.44269504f);
                    rsum[r] += p;
                    sPw[(quad * 4 + r) * PSTR + ni * 16 + l15] = f2bf(p);
                }
            }
#pragma unroll
            for (int off = 1; off < 16; off <<= 1)
#pragma unroll
                for (int r = 0; r < 4; r++) rsum[r] += __shfl_xor(rsum[r], off, 64);
#pragma unroll
            for (int r = 0; r < 4; r++) l_i[r] = l_i[r] * alpha[r] + rsum[r];
#pragma unroll
            for (int t = 0; t < 8; t++)
#pragma unroll
                for (int r = 0; r < 4; r++) O[t][r] *= alpha[r];

            __syncthreads();

#pragma unroll
            for (int ks2 = 0; ks2 < 4; ks2++) {
                short8 aP = *(const short8*)&sPw[l15 * PSTR + ks2 * 32 + quad * 8];
#pragma unroll
                for (int t = 0; t < 8; t++) {
                    short8 bV = *(const short8*)&sVt[(t * 16 + l15) * VTSTR + ks2 * 32 + quad * 8];
                    O[t] = __builtin_amdgcn_mfma_f32_16x16x32_bf16(aP, bV, O[t], 0, 0, 0);
                }
            }
        }

        const int b = bh >> 4, h = bh & 15;
#pragma unroll
        for (int r = 0; r < 4; r++) {
            float inv = 1.0f / l_i[r];
            int srow = qt * 128 + w * 16 + quad * 4 + r;
            size_t rowoff = ((size_t)(b * S_LEN + srow)) * DIMN + h * DHEAD;
#pragma unroll
            for (int t = 0; t < 8; t++)
                ctx[rowoff + t * 16 + l15] = f2bf(O[t][r] * inv);
        }
    }
}

// ---------------------------------------------------------------------------
extern "C" void kernel_launch(void* const* d_in, const int* in_sizes, int n_in,
                              void* d_out, int out_size, void* d_ws, size_t ws_size,
                              hipStream_t stream)
{
    const float* x     = (const float*)d_in[0];
    // d_in[1] = causal mask (bool) — deterministic tril, masking hard-coded
    const float* Wq    = (const float*)d_in[2];
    const float* bq    = (const float*)d_in[3];
    const float* Wk    = (const float*)d_in[4];
    const float* bk    = (const float*)d_in[5];
    const float* Wv    = (const float*)d_in[6];
    const float* bv    = (const float*)d_in[7];
    const float* Wo    = (const float*)d_in[8];
    const float* bo    = (const float*)d_in[9];
    const float* scale = (const float*)d_in[10];

    const int M = 4096, N = 2048, K = 2048;
    float* out = (float*)d_out;
    const size_t need = (SEGQ + 4 * SEGW + 3 * SEGQ) * sizeof(unsigned short); // 100.7 MB

    if (ws_size >= need) {
        // Fast path: bf16 operands; 8-phase fused QKV GEMM (+L2 norm).
        unsigned short* xb  = (unsigned short*)d_ws;   // ctx aliases xb (dead after QKV)
        unsigned short* wqb = xb  + SEGQ;              // wqb|wkb|wvb contiguous = fused B
        unsigned short* wkb = wqb + SEGW;
        unsigned short* wvb = wkb + SEGW;
        unsigned short* wob = wvb + SEGW;
        unsigned short* qn  = wob + SEGW;              // qn|kn|vt contiguous
        unsigned short* kn  = qn  + SEGQ;
        unsigned short* vtb = kn  + SEGQ;
        unsigned short* ctx = xb;

        cvt5_kernel<<<dim3(512, 5), 256, 0, stream>>>(x, Wq, Wk, Wv, Wo,
                                                      xb, wqb, wkb, wvb, wob);
        gemm8<<<dim3(24, 16), 512, 0, stream>>>(xb, wqb, bq, bk, bv, scale, qn, M, 6144, K);
        attn_kernel4<<<dim3(8, 32), 512, 0, stream>>>(qn, kn, vtb, ctx);
        gemm3<1><<<dim3(16, 16), 512, 0, stream>>>(ctx, wob, bo, nullptr, nullptr, nullptr, out, M, N, K);
    } else {
        // Fallback (67 MB): fp32 operands converted during staging.
        unsigned short* qn  = (unsigned short*)d_ws;
        unsigned short* kn  = qn + SEGQ;
        unsigned short* vtb = kn + SEGQ;
        unsigned short* ctx = vtb + SEGQ;

        gemm_bt<1, 1, 0><<<dim3(16, 32), 256, 0, stream>>>(x, Wq, bq, qn, M, N, K);
        gemm_bt<1, 1, 0><<<dim3(16, 32), 256, 0, stream>>>(x, Wk, bk, kn, M, N, K);
        gemm_bt<2, 1, 0><<<dim3(16, 32), 256, 0, stream>>>(x, Wv, bv, vtb, M, N, K);
        l2norm_kernel<<<dim3(16384, 2), 256, 0, stream>>>(qn, kn, scale);
        attn_kernel4<<<dim3(8, 32), 512, 0, stream>>>(qn, kn, vtb, ctx);
        gemm_bt<0, 0, 1><<<dim3(16, 32), 256, 0, stream>>>(ctx, Wo, bo, out, M, N, K);
    }
}

// Round 6
// 402.678 us; speedup vs baseline: 1.1121x; 1.0823x over previous
//
#include <hip/hip_runtime.h>
#include <hip/hip_bf16.h>

// Problem constants (BS=2, SLEN=2048, DIM=2048, H=16, DH=128)
// I/O dtype: fp32. Internals: bf16 MFMA, fp32 accumulation, bf16 workspace.
#define S_LEN 2048
#define DIMN  2048
#define NHEAD 16
#define DHEAD 128
#define SEGQ  ((size_t)4096 * 2048)
#define SEGW  ((size_t)2048 * 2048)

typedef __attribute__((ext_vector_type(8))) short short8;
typedef __attribute__((ext_vector_type(4))) float floatx4;

__device__ inline float bf2f(unsigned short u) {
    union { unsigned int i; float f; } v; v.i = ((unsigned int)u) << 16; return v.f;
}
__device__ inline unsigned short f2bf(float f) {
    unsigned int x = __float_as_uint(f);
    unsigned int r = (x + 0x7FFFu + ((x >> 16) & 1u)) >> 16;  // RNE
    return (unsigned short)r;
}
__device__ inline short8 ld8_f32_as_bf16(const float* p) {
    float4 a = *(const float4*)p;
    float4 b = *(const float4*)(p + 4);
    short8 r;
    r[0] = (short)f2bf(a.x); r[1] = (short)f2bf(a.y);
    r[2] = (short)f2bf(a.z); r[3] = (short)f2bf(a.w);
    r[4] = (short)f2bf(b.x); r[5] = (short)f2bf(b.y);
    r[6] = (short)f2bf(b.z); r[7] = (short)f2bf(b.w);
    return r;
}
// Async global->LDS, 16B/lane; LDS base wave-uniform, lane i at +i*16.
__device__ inline void glds16(unsigned short* lds, const unsigned short* g) {
    __builtin_amdgcn_global_load_lds(
        (const __attribute__((address_space(1))) unsigned int*)g,
        (__attribute__((address_space(3))) unsigned int*)lds, 16, 0, 0);
}

// ---------------------------------------------------------------------------
// One-shot fp32 -> bf16 conversion of x, Wq, Wk, Wv, Wo (blockIdx.y selects).
// ---------------------------------------------------------------------------
__global__ __launch_bounds__(256) void cvt5_kernel(
    const float* __restrict__ s0, const float* __restrict__ s1,
    const float* __restrict__ s2, const float* __restrict__ s3,
    const float* __restrict__ s4,
    unsigned short* __restrict__ d0, unsigned short* __restrict__ d1,
    unsigned short* __restrict__ d2, unsigned short* __restrict__ d3,
    unsigned short* __restrict__ d4)
{
    const float* s; unsigned short* d; size_t n;
    switch (blockIdx.y) {
        case 0:  s = s0; d = d0; n = SEGQ; break;
        case 1:  s = s1; d = d1; n = SEGW; break;
        case 2:  s = s2; d = d2; n = SEGW; break;
        case 3:  s = s3; d = d3; n = SEGW; break;
        default: s = s4; d = d4; n = SEGW; break;
    }
    size_t stride = (size_t)gridDim.x * 256 * 8;
    for (size_t i = ((size_t)blockIdx.x * 256 + threadIdx.x) * 8; i < n; i += stride)
        *(short8*)&d[i] = ld8_f32_as_bf16(&s[i]);
}

// ---------------------------------------------------------------------------
// gemm3 (R2-verified, 141 us on QKV): counted-vmcnt 3-buffer pipelined GEMM.
//   BM=256, BN=128, BK=32, 512 thr = 8 waves (4M x 2N), 64x64 per wave.
//   Stage K-tile t+2 while computing t; ONE raw s_barrier + ONE counted
//   s_waitcnt vmcnt(3) per K-tile (tail vmcnt(0)); no __syncthreads in loop.
//   LDS 3 x 24 KB = 72 KB -> 2 blocks/CU (cross-block de-phasing provides
//   the LDS/MFMA overlap; journal R3/R5: bigger wave-tiles or 8-phase
//   lockstep both LOST to this -- 169/158 vs 141).
//   Swizzle (both-sides involution, rule #21): linear glds dest, source col
//   colE = (l&3)*8 ^ ((l>>3)&3)<<3, read col cs = quad*8 ^ ((l15>>1)&3)<<3.
// EPI=0: fused QKV epilogue with in-epilogue L2 norm (n-tile = one head).
// EPI=1: fp32 flat output + bias.
// ---------------------------------------------------------------------------
#define BUFE (384 * 32)   // elements per buffer: A 256x32 + B 128x32

template <int EPI>
__global__ __launch_bounds__(512) void gemm3(
    const unsigned short* __restrict__ A, const unsigned short* __restrict__ Bw,
    const float* __restrict__ b0, const float* __restrict__ b1,
    const float* __restrict__ b2, const float* __restrict__ scale_p,
    void* __restrict__ Cp, int M, int N, int K)
{
    __shared__ __align__(16) unsigned short sBuf[3 * BUFE];   // 73728 B

    const int tid  = threadIdx.x;
    const int w    = tid >> 6, lane = tid & 63;
    const int l15  = lane & 15, quad = lane >> 4;
    const int wr   = w >> 1, wc = w & 1;            // 4M x 2N waves
    const int tm   = blockIdx.y * 256, tn = blockIdx.x * 128;

    const int colE = ((lane & 3) * 8) ^ (((lane >> 3) & 3) << 3);
    const int cs   = (quad * 8) ^ (((l15 >> 1) & 3) << 3);
    const int srow = w * 16 + (lane >> 2);          // 0..127 staging row

    floatx4 acc[4][4] = {};

    auto stage = [&](int kt, int bsel) {
        const int k0 = kt * 32;
        glds16(&sBuf[bsel * BUFE + 0 * 4096 + w * 512],
               &A[(size_t)(tm + srow) * K + k0 + colE]);
        glds16(&sBuf[bsel * BUFE + 1 * 4096 + w * 512],
               &A[(size_t)(tm + 128 + srow) * K + k0 + colE]);
        glds16(&sBuf[bsel * BUFE + 8192 + w * 512],
               &Bw[(size_t)(tn + srow) * K + k0 + colE]);
    };

    const int nT = K >> 5;            // 64 K-tiles
    stage(0, 0);
    stage(1, 1);

    int bs = 0;
    for (int t = 0; t < nT; ++t) {
        if (t < nT - 1) asm volatile("s_waitcnt vmcnt(3)" ::: "memory");
        else            asm volatile("s_waitcnt vmcnt(0)" ::: "memory");
        __builtin_amdgcn_s_barrier();
        __builtin_amdgcn_sched_barrier(0);

        const unsigned short* bufA = &sBuf[bs * BUFE];
        const unsigned short* bufB = bufA + 8192;
        short8 af[4], bfr[4];
#pragma unroll
        for (int mi = 0; mi < 4; mi++)
            af[mi] = *(const short8*)&bufA[(wr * 64 + mi * 16 + l15) * 32 + cs];
#pragma unroll
        for (int ni = 0; ni < 4; ni++)
            bfr[ni] = *(const short8*)&bufB[(wc * 64 + ni * 16 + l15) * 32 + cs];

        if (t + 2 < nT) stage(t + 2, bs == 0 ? 2 : bs - 1);

        __builtin_amdgcn_s_setprio(1);
#pragma unroll
        for (int mi = 0; mi < 4; mi++)
#pragma unroll
            for (int ni = 0; ni < 4; ni++)
                acc[mi][ni] = __builtin_amdgcn_mfma_f32_16x16x32_bf16(af[mi], bfr[ni], acc[mi][ni], 0, 0, 0);
        __builtin_amdgcn_s_setprio(0);

        bs = (bs == 2) ? 0 : bs + 1;
    }
    __syncthreads();   // loop done, nothing outstanding; safe full drain

    // Epilogue: C/D layout row = quad*4 + r, col = l15 (m89-verified)
    if (EPI == 0) {
        const int t = tn >> 11;
        const float* bp = (t == 0) ? b0 : (t == 1) ? b1 : b2;
        unsigned short* Q = (unsigned short*)Cp;
        // bias first (reference normalizes x@W.T + b)
#pragma unroll
        for (int ni = 0; ni < 4; ni++) {
            int n = tn + wc * 64 + ni * 16 + l15;
            float bias = bp[n & 2047];
#pragma unroll
            for (int mi = 0; mi < 4; mi++)
#pragma unroll
                for (int r = 0; r < 4; r++) acc[mi][ni][r] += bias;
        }
        // per-row sum of squares over this wave's 64-dh half
        float ssq[4][4];
#pragma unroll
        for (int mi = 0; mi < 4; mi++)
#pragma unroll
            for (int r = 0; r < 4; r++) {
                float s = 0.0f;
#pragma unroll
                for (int ni = 0; ni < 4; ni++) s += acc[mi][ni][r] * acc[mi][ni][r];
#pragma unroll
                for (int off = 1; off < 16; off <<= 1) s += __shfl_xor(s, off, 64);
                ssq[mi][r] = s;
            }
        float* ssh = (float*)sBuf;      // 512 floats, reuse sBuf
        if (l15 == 0) {
#pragma unroll
            for (int mi = 0; mi < 4; mi++)
#pragma unroll
                for (int r = 0; r < 4; r++)
                    ssh[wc * 256 + wr * 64 + mi * 16 + quad * 4 + r] = ssq[mi][r];
        }
        __syncthreads();
        const float scl = (t == 0) ? scale_p[0] : 1.0f;
#pragma unroll
        for (int mi = 0; mi < 4; mi++) {
            int mbase = tm + wr * 64 + mi * 16 + quad * 4;
#pragma unroll
            for (int r = 0; r < 4; r++) {
                float tot = ssq[mi][r] + ssh[(wc ^ 1) * 256 + wr * 64 + mi * 16 + quad * 4 + r];
                float f = (t < 2) ? rsqrtf(tot) * scl : 1.0f;
                int m = mbase + r;
                int b = m >> 11, s = m & 2047;
#pragma unroll
                for (int ni = 0; ni < 4; ni++) {
                    int n = tn + wc * 64 + ni * 16 + l15;
                    int h = (n >> 7) & 15, dh = n & 127;
                    float v = acc[mi][ni][r] * f;
                    size_t idx = (t < 2)
                        ? (size_t)t * SEGQ + (((size_t)(b * NHEAD + h)) * S_LEN + s) * DHEAD + dh
                        : 2 * SEGQ + (((size_t)(b * NHEAD + h)) * DHEAD + dh) * S_LEN + s;
                    Q[idx] = f2bf(v);
                }
            }
        }
    } else {
#pragma unroll
        for (int mi = 0; mi < 4; mi++) {
            int mbase = tm + wr * 64 + mi * 16 + quad * 4;
#pragma unroll
            for (int ni = 0; ni < 4; ni++) {
                int n = tn + wc * 64 + ni * 16 + l15;
                float bias = b0[n];
#pragma unroll
                for (int r = 0; r < 4; r++) {
                    int m = mbase + r;
                    ((float*)Cp)[(size_t)m * N + n] = acc[mi][ni][r] + bias;
                }
            }
        }
    }
}

// ---------------------------------------------------------------------------
// Fallback GEMM: fp32 A/B converted during staging.
// SPLIT: 0 none, 1 (b,h,s,dh), 2 transposed V (b,h,dh,s).
// ---------------------------------------------------------------------------
template <int SPLIT, int A_F32, int OUT_F32>
__global__ __launch_bounds__(256) void gemm_bt(
    const void* __restrict__ Ap, const float* __restrict__ Bw,
    const float* __restrict__ bias, void* __restrict__ Cp,
    int M, int N, int K)
{
    __shared__ __align__(16) unsigned short sA[128 * 40];
    __shared__ __align__(16) unsigned short sB[128 * 40];

    const int tid  = threadIdx.x;
    const int w    = tid >> 6, lane = tid & 63;
    const int l15  = lane & 15, quad = lane >> 4;
    const int wm   = w >> 1, wn = w & 1;
    const int tm   = blockIdx.y * 128, tn = blockIdx.x * 128;

    const float*          Af32 = (const float*)Ap;
    const unsigned short* Abf  = (const unsigned short*)Ap;

    floatx4 acc[4][4] = {};

    for (int k0 = 0; k0 < K; k0 += 32) {
        __syncthreads();
#pragma unroll
        for (int i = 0; i < 2; i++) {
            int c   = tid + i * 256;
            int row = c >> 2;
            int kc  = (c & 3) * 8;
            size_t goff = (size_t)(tm + row) * K + k0 + kc;
            if (A_F32)
                *(short8*)&sA[row * 40 + kc] = ld8_f32_as_bf16(&Af32[goff]);
            else
                *(short8*)&sA[row * 40 + kc] = *(const short8*)&Abf[goff];
            *(short8*)&sB[row * 40 + kc] =
                ld8_f32_as_bf16(&Bw[(size_t)(tn + row) * K + k0 + kc]);
        }
        __syncthreads();

        short8 af[4], bfr[4];
#pragma unroll
        for (int mi = 0; mi < 4; mi++)
            af[mi] = *(const short8*)&sA[(wm * 64 + mi * 16 + l15) * 40 + quad * 8];
#pragma unroll
        for (int ni = 0; ni < 4; ni++)
            bfr[ni] = *(const short8*)&sB[(wn * 64 + ni * 16 + l15) * 40 + quad * 8];
#pragma unroll
        for (int mi = 0; mi < 4; mi++)
#pragma unroll
            for (int ni = 0; ni < 4; ni++)
                acc[mi][ni] = __builtin_amdgcn_mfma_f32_16x16x32_bf16(af[mi], bfr[ni], acc[mi][ni], 0, 0, 0);
    }

#pragma unroll
    for (int mi = 0; mi < 4; mi++) {
        int mbase = tm + wm * 64 + mi * 16 + quad * 4;
#pragma unroll
        for (int ni = 0; ni < 4; ni++) {
            int n = tn + wn * 64 + ni * 16 + l15;
            float bv = bias[n];
#pragma unroll
            for (int r = 0; r < 4; r++) {
                int m = mbase + r;
                float v = acc[mi][ni][r] + bv;
                if (SPLIT == 1) {
                    int b = m >> 11, s = m & 2047, h = n >> 7, dh = n & 127;
                    ((unsigned short*)Cp)[(((size_t)(b * NHEAD + h)) * S_LEN + s) * DHEAD + dh] = f2bf(v);
                } else if (SPLIT == 2) {
                    int b = m >> 11, s = m & 2047, h = n >> 7, dh = n & 127;
                    ((unsigned short*)Cp)[(((size_t)(b * NHEAD + h)) * DHEAD + dh) * S_LEN + s] = f2bf(v);
                } else if (OUT_F32) {
                    ((float*)Cp)[(size_t)m * N + n] = v;
                } else {
                    ((unsigned short*)Cp)[(size_t)m * N + n] = f2bf(v);
                }
            }
        }
    }
}

// ---------------------------------------------------------------------------
// Fallback-path L2 norm (fast path fuses it into the QKV epilogue).
// ---------------------------------------------------------------------------
__global__ __launch_bounds__(256) void l2norm_kernel(
    unsigned short* __restrict__ qn, unsigned short* __restrict__ kn,
    const float* __restrict__ scale_p)
{
    const int w = threadIdx.x >> 6, lane = threadIdx.x & 63;
    size_t row = (size_t)blockIdx.x * 4 + w;
    unsigned short* base = (blockIdx.y == 0 ? qn : kn) + row * DHEAD;
    float a = bf2f(base[lane * 2]);
    float b = bf2f(base[lane * 2 + 1]);
    float ss = a * a + b * b;
#pragma unroll
    for (int off = 1; off < 64; off <<= 1) ss += __shfl_xor(ss, off, 64);
    float f = rsqrtf(ss);
    if (blockIdx.y == 0) f *= scale_p[0];
    base[lane * 2]     = f2bf(a * f);
    base[lane * 2 + 1] = f2bf(b * f);
}

// ---------------------------------------------------------------------------
// Flash attention v5: v4 structure (128x128 tiles, 8-wave blocks, grid
// (8,32), Q-tile pairs {x,15-x}, 17 kt-iters, 1-deep register prefetch)
// with three R5 changes:
//  1. Softmax->PV __syncthreads REMOVED: sP is wave-private (writes rows
//     quad*4+r, reads rows l15, both in sPw); same-wave LDS RAW is ordered
//     by compiler lgkmcnt. Saves 17 full block drains per block.
//  2. setprio(1/0) around QK^T and PV MFMA clusters (T5, attn-proven m191).
//  3. XCD-aware remap (T1): lin = x + 8y round-robins XCDs; remap packs the
//     8 blocks of a head (and 4 heads = 4 MB K/V = one L2) on one XCD:
//     xb = (lin>>3)&7, bh = ((lin&7)<<2)|(lin>>6)  [bijective on 256].
// LDS: 3 x 34816 B = 102 KiB -> 1 block/CU.
// ---------------------------------------------------------------------------
#define KSTR  136   // 272B rows: 16B-aligned, 2-way banks (free per m136)
#define VTSTR 136
#define PSTR  136

__global__ __launch_bounds__(512) void attn_kernel5(
    const unsigned short* __restrict__ qn, const unsigned short* __restrict__ kn,
    const unsigned short* __restrict__ vt, unsigned short* __restrict__ ctx)
{
    __shared__ __align__(16) unsigned short sK [128 * KSTR];
    __shared__ __align__(16) unsigned short sVt[128 * VTSTR];
    __shared__ __align__(16) unsigned short sP [8 * 16 * PSTR];

    const int tid  = threadIdx.x;
    const int w    = tid >> 6, lane = tid & 63;   // w in [0,8)
    const int l15  = lane & 15, quad = lane >> 4;
    const int lin  = blockIdx.x + (blockIdx.y << 3);
    const int xb   = (lin >> 3) & 7;
    const int bh   = ((lin & 7) << 2) | (lin >> 6);
    const size_t headoff = (size_t)bh * S_LEN * DHEAD;
    const unsigned short* kbase0 = kn + headoff;
    const unsigned short* vtbase = vt + headoff;   // [dh][s] within head
    unsigned short* sPw = sP + w * 16 * PSTR;

    short8 kpre[4], vpre[4];

    for (int half = 0; half < 2; half++) {
        const int qt = half ? (15 - xb) : xb;      // 128-row Q tiles

        const unsigned short* qrow = qn + headoff + (size_t)(qt * 128 + w * 16 + l15) * DHEAD;
        short8 aQ[4];
#pragma unroll
        for (int ks = 0; ks < 4; ks++) aQ[ks] = *(const short8*)(qrow + ks * 32 + quad * 8);

        floatx4 O[8] = {};
        float m_i[4], l_i[4];
#pragma unroll
        for (int r = 0; r < 4; r++) { m_i[r] = -1e30f; l_i[r] = 0.0f; }

        if (half == 0) {  // prefetch kt=0 (half 1 gets it from half 0's tail)
#pragma unroll
            for (int j = 0; j < 4; j++) {
                int c = tid + j * 512;   // 128x128 tile = 2048 16B chunks
                kpre[j] = *(const short8*)(kbase0 + (size_t)(c >> 4) * DHEAD + (c & 15) * 8);
                vpre[j] = *(const short8*)(vtbase + (size_t)(c >> 4) * S_LEN + (c & 15) * 8);
            }
        }

        for (int kt = 0; kt <= qt; kt++) {
            __syncthreads();   // previous iteration's LDS reads complete (WAR)

            // Commit prefetched K-tile and V^T-tile (all ds_write_b128)
#pragma unroll
            for (int j = 0; j < 4; j++) {
                int c = tid + j * 512;
                *(short8*)&sK [(c >> 4) * KSTR  + (c & 15) * 8] = kpre[j];
                *(short8*)&sVt[(c >> 4) * VTSTR + (c & 15) * 8] = vpre[j];
            }

            // Prefetch next tile (next kt, or kt=0 for the second Q-tile)
            if (kt < qt || half == 0) {
                const int knext = (kt < qt) ? (kt + 1) * 128 : 0;
#pragma unroll
                for (int j = 0; j < 4; j++) {
                    int c = tid + j * 512;
                    kpre[j] = *(const short8*)(kbase0 + (size_t)(knext + (c >> 4)) * DHEAD + (c & 15) * 8);
                    vpre[j] = *(const short8*)(vtbase + (size_t)(c >> 4) * S_LEN + knext + (c & 15) * 8);
                }
            }
            __syncthreads();

            // S = Q K^T (wave strip 16 x 128)
            floatx4 sc[8] = {};
            __builtin_amdgcn_s_setprio(1);
#pragma unroll
            for (int ks = 0; ks < 4; ks++) {
#pragma unroll
                for (int ni = 0; ni < 8; ni++) {
                    short8 bK = *(const short8*)&sK[(ni * 16 + l15) * KSTR + ks * 32 + quad * 8];
                    sc[ni] = __builtin_amdgcn_mfma_f32_16x16x32_bf16(aQ[ks], bK, sc[ni], 0, 0, 0);
                }
            }
            __builtin_amdgcn_s_setprio(0);

            if (kt == qt) {  // causal mask within diagonal tile
#pragma unroll
                for (int ni = 0; ni < 8; ni++) {
                    int cl = ni * 16 + l15;
#pragma unroll
                    for (int r = 0; r < 4; r++) {
                        int rl = w * 16 + quad * 4 + r;
                        if (cl > rl) sc[ni][r] = -1e30f;
                    }
                }
            }

            // Online softmax (stats replicated across the 16 lanes of a quad)
            float rmax[4];
#pragma unroll
            for (int r = 0; r < 4; r++) {
                float mx = sc[0][r];
#pragma unroll
                for (int ni = 1; ni < 8; ni++) mx = fmaxf(mx, sc[ni][r]);
                rmax[r] = mx;
            }
#pragma unroll
            for (int off = 1; off < 16; off <<= 1)
#pragma unroll
                for (int r = 0; r < 4; r++) rmax[r] = fmaxf(rmax[r], __shfl_xor(rmax[r], off, 64));

            float alpha[4], rsum[4];
#pragma unroll
            for (int r = 0; r < 4; r++) {
                float mn = fmaxf(m_i[r], rmax[r]);
                alpha[r] = exp2f((m_i[r] - mn) * 1.44269504f);
                m_i[r] = mn;
                rsum[r] = 0.0f;
            }
#pragma unroll
            for (int ni = 0; ni < 8; ni++) {
#pragma unroll
                for (int r = 0; r < 4; r++) {
                    float p = exp2f((sc[ni][r] - m_i[r]) * 1.44269504f);
                    rsum[r] += p;
                    sPw[(quad * 4 + r) * PSTR + ni * 16 + l15] = f2bf(p);
                }
            }
#pragma unroll
            for (int off = 1; off < 16; off <<= 1)
#pragma unroll
                for (int r = 0; r < 4; r++) rsum[r] += __shfl_xor(rsum[r], off, 64);
#pragma unroll
            for (int r = 0; r < 4; r++) l_i[r] = l_i[r] * alpha[r] + rsum[r];
#pragma unroll
            for (int t = 0; t < 8; t++)
#pragma unroll
                for (int r = 0; r < 4; r++) O[t][r] *= alpha[r];

            // NOTE: no barrier here (R5). sP traffic is wave-private; the
            // compiler's lgkmcnt orders this wave's P writes before its reads.

            // O += P V   (k-dim = 128 keys)
            __builtin_amdgcn_s_setprio(1);
#pragma unroll
            for (int ks2 = 0; ks2 < 4; ks2++) {
                short8 aP = *(const short8*)&sPw[l15 * PSTR + ks2 * 32 + quad * 8];
#pragma unroll
                for (int t = 0; t < 8; t++) {
                    short8 bV = *(const short8*)&sVt[(t * 16 + l15) * VTSTR + ks2 * 32 + quad * 8];
                    O[t] = __builtin_amdgcn_mfma_f32_16x16x32_bf16(aP, bV, O[t], 0, 0, 0);
                }
            }
            __builtin_amdgcn_s_setprio(0);
        }

        // Epilogue: ctx[b, s, h*128 + dh] = O / l
        const int b = bh >> 4, h = bh & 15;
#pragma unroll
        for (int r = 0; r < 4; r++) {
            float inv = 1.0f / l_i[r];
            int srow = qt * 128 + w * 16 + quad * 4 + r;
            size_t rowoff = ((size_t)(b * S_LEN + srow)) * DIMN + h * DHEAD;
#pragma unroll
            for (int t = 0; t < 8; t++)
                ctx[rowoff + t * 16 + l15] = f2bf(O[t][r] * inv);
        }
    }
}

// ---------------------------------------------------------------------------
extern "C" void kernel_launch(void* const* d_in, const int* in_sizes, int n_in,
                              void* d_out, int out_size, void* d_ws, size_t ws_size,
                              hipStream_t stream)
{
    const float* x     = (const float*)d_in[0];
    // d_in[1] = causal mask (bool) — deterministic tril, masking hard-coded
    const float* Wq    = (const float*)d_in[2];
    const float* bq    = (const float*)d_in[3];
    const float* Wk    = (const float*)d_in[4];
    const float* bk    = (const float*)d_in[5];
    const float* Wv    = (const float*)d_in[6];
    const float* bv    = (const float*)d_in[7];
    const float* Wo    = (const float*)d_in[8];
    const float* bo    = (const float*)d_in[9];
    const float* scale = (const float*)d_in[10];

    const int M = 4096, N = 2048, K = 2048;
    float* out = (float*)d_out;
    const size_t need = (SEGQ + 4 * SEGW + 3 * SEGQ) * sizeof(unsigned short); // 100.7 MB

    if (ws_size >= need) {
        // Fast path: bf16 operands; pipelined fused QKV GEMM (+L2 norm).
        unsigned short* xb  = (unsigned short*)d_ws;   // ctx aliases xb (dead after QKV)
        unsigned short* wqb = xb  + SEGQ;              // wqb|wkb|wvb contiguous = fused B
        unsigned short* wkb = wqb + SEGW;
        unsigned short* wvb = wkb + SEGW;
        unsigned short* wob = wvb + SEGW;
        unsigned short* qn  = wob + SEGW;              // qn|kn|vt contiguous
        unsigned short* kn  = qn  + SEGQ;
        unsigned short* vtb = kn  + SEGQ;
        unsigned short* ctx = xb;

        cvt5_kernel<<<dim3(512, 5), 256, 0, stream>>>(x, Wq, Wk, Wv, Wo,
                                                      xb, wqb, wkb, wvb, wob);
        gemm3<0><<<dim3(48, 16), 512, 0, stream>>>(xb, wqb, bq, bk, bv, scale, qn, M, 6144, K);
        attn_kernel5<<<dim3(8, 32), 512, 0, stream>>>(qn, kn, vtb, ctx);
        gemm3<1><<<dim3(16, 16), 512, 0, stream>>>(ctx, wob, bo, nullptr, nullptr, nullptr, out, M, N, K);
    } else {
        // Fallback (67 MB): fp32 operands converted during staging.
        unsigned short* qn  = (unsigned short*)d_ws;
        unsigned short* kn  = qn + SEGQ;
        unsigned short* vtb = kn + SEGQ;
        unsigned short* ctx = vtb + SEGQ;

        gemm_bt<1, 1, 0><<<dim3(16, 32), 256, 0, stream>>>(x, Wq, bq, qn, M, N, K);
        gemm_bt<1, 1, 0><<<dim3(16, 32), 256, 0, stream>>>(x, Wk, bk, kn, M, N, K);
        gemm_bt<2, 1, 0><<<dim3(16, 32), 256, 0, stream>>>(x, Wv, bv, vtb, M, N, K);
        l2norm_kernel<<<dim3(16384, 2), 256, 0, stream>>>(qn, kn, scale);
        attn_kernel5<<<dim3(8, 32), 512, 0, stream>>>(qn, kn, vtb, ctx);
        gemm_bt<0, 0, 1><<<dim3(16, 32), 256, 0, stream>>>(ctx, Wo, bo, out, M, N, K);
    }
}